// Round 2
// baseline (248.612 us; speedup 1.0000x reference)
//
#include <hip/hip_runtime.h>
#include <hip/hip_bf16.h>
#include <math.h>

typedef __attribute__((ext_vector_type(8))) __bf16 bf16x8;
typedef __attribute__((ext_vector_type(4))) __bf16 bf16x4;
typedef __attribute__((ext_vector_type(4))) float f32x4;

#define NTOK 4096
#define DHEAD 32

// ---------------- Kernel 1: QKV projection (fp32 in, bf16 out) ----------------
// qkv[b][o][n] = sum_c w[o][c] * x[b][c][n]; o<128 -> Q (scaled by 1/sqrt(32)*log2(e)),
// 128..255 -> K, 256..383 -> V stored transposed as VT[b][h][d][n].
__global__ __launch_bounds__(256) void qkv_proj_kernel(const float* __restrict__ x,
                                                       const float* __restrict__ w,
                                                       __bf16* __restrict__ Qo,
                                                       __bf16* __restrict__ Ko,
                                                       __bf16* __restrict__ Vo)
{
    __shared__ float xt[128 * 64];
    const int bid = blockIdx.x;          // 256 blocks: b(2) x ntile(64) x osplit(2)
    const int os  = bid & 1;
    const int nt  = (bid >> 1) & 63;
    const int b   = bid >> 7;
    const int n0  = nt * 64;
    const int tid = threadIdx.x;
    const float* xb = x + (size_t)b * 128 * NTOK + n0;
    for (int idx = tid; idx < 128 * 64; idx += 256) {
        int c = idx >> 6, j = idx & 63;
        xt[idx] = xb[(size_t)c * NTOK + j];
    }
    __syncthreads();
    const int j = tid & 63, wrow = tid >> 6;   // wrow uniform per wave -> scalar w loads
    const int n = n0 + j;
    const float qscale = 0.2550316626f;        // (1/sqrt(32)) * log2(e)
    for (int kk = 0; kk < 48; kk += 8) {
        float a[8] = {0.f,0.f,0.f,0.f,0.f,0.f,0.f,0.f};
        for (int c = 0; c < 128; ++c) {
            float xv = xt[c * 64 + j];
            #pragma unroll
            for (int u = 0; u < 8; ++u) {
                const int o = os * 192 + (kk + u) * 4 + wrow;
                a[u] = fmaf(w[o * 128 + c], xv, a[u]);
            }
        }
        #pragma unroll
        for (int u = 0; u < 8; ++u) {
            const int o = os * 192 + (kk + u) * 4 + wrow;
            float v = a[u];
            if (o < 128) {
                const int h = o >> 5, d = o & 31;
                Qo[((size_t)(b * 4 + h) * NTOK + n) * DHEAD + d] = (__bf16)(v * qscale);
            } else if (o < 256) {
                const int oo = o - 128, h = oo >> 5, d = oo & 31;
                Ko[((size_t)(b * 4 + h) * NTOK + n) * DHEAD + d] = (__bf16)v;
            } else {
                const int oo = o - 256, h = oo >> 5, d = oo & 31;
                Vo[((size_t)(b * 4 + h) * DHEAD + d) * NTOK + n] = (__bf16)v;
            }
        }
    }
}

// ---------------- Kernel 2: flash attention, swapped QK^T, no LDS ----------------
// One wave per block, 32 q-rows per wave (2 x 16-row tiles), KV block = 32.
// S^T tile via mfma(A=K rows, B=Q): lane l holds S[kv=4g+r][q=l&15] (C/D layout HW-verified).
// PV as out^T = V^T * P^T with the SAME lane-local slot->kv bijection on both operands.
__global__ __launch_bounds__(64) void attn_kernel(const __bf16* __restrict__ Q,
                                                  const __bf16* __restrict__ K,
                                                  const __bf16* __restrict__ VT,
                                                  float* __restrict__ ot)
{
    const int bid  = blockIdx.x;      // 1024 = 8 bh * 128 q-groups
    const int bh   = bid >> 7;
    const int qg   = bid & 127;
    const int lane = threadIdx.x;
    const int g = lane >> 4, ql = lane & 15;
    const __bf16* Qb = Q  + (size_t)bh * NTOK * DHEAD;
    const __bf16* Kb = K  + (size_t)bh * NTOK * DHEAD;
    const __bf16* Vb = VT + (size_t)bh * DHEAD * NTOK;
    const int q0 = qg * 32;

    // Q fragments (persistent): lane reads Q[q0+qt*16+ql][8g..8g+8)
    bf16x8 qf0 = *(const bf16x8*)(Qb + (size_t)(q0 + ql) * DHEAD + g * 8);
    bf16x8 qf1 = *(const bf16x8*)(Qb + (size_t)(q0 + 16 + ql) * DHEAD + g * 8);

    f32x4 acc00 = {0.f,0.f,0.f,0.f};  // [qt][dtile] numerators of out^T
    f32x4 acc01 = acc00, acc10 = acc00, acc11 = acc00;
    float m0 = -1e30f, m1 = -1e30f, l0 = 0.f, l1 = 0.f;

    // prefetch kv-block 0
    bf16x8 kf0 = *(const bf16x8*)(Kb + (size_t)ql * DHEAD + g * 8);
    bf16x8 kf1 = *(const bf16x8*)(Kb + (size_t)(16 + ql) * DHEAD + g * 8);
    bf16x4 v00 = *(const bf16x4*)(Vb + (size_t)ql * NTOK + 4 * g);
    bf16x4 v01 = *(const bf16x4*)(Vb + (size_t)ql * NTOK + 16 + 4 * g);
    bf16x4 v10 = *(const bf16x4*)(Vb + (size_t)(16 + ql) * NTOK + 4 * g);
    bf16x4 v11 = *(const bf16x4*)(Vb + (size_t)(16 + ql) * NTOK + 16 + 4 * g);

    for (int kv0 = 0; kv0 < NTOK; kv0 += 32) {
        // prefetch next block (wraps on last iter; harmless, stays in-bounds)
        const int kvn = (kv0 + 32) & (NTOK - 1);
        bf16x8 nkf0 = *(const bf16x8*)(Kb + (size_t)(kvn + ql) * DHEAD + g * 8);
        bf16x8 nkf1 = *(const bf16x8*)(Kb + (size_t)(kvn + 16 + ql) * DHEAD + g * 8);
        bf16x4 nv00 = *(const bf16x4*)(Vb + (size_t)ql * NTOK + kvn + 4 * g);
        bf16x4 nv01 = *(const bf16x4*)(Vb + (size_t)ql * NTOK + kvn + 16 + 4 * g);
        bf16x4 nv10 = *(const bf16x4*)(Vb + (size_t)(16 + ql) * NTOK + kvn + 4 * g);
        bf16x4 nv11 = *(const bf16x4*)(Vb + (size_t)(16 + ql) * NTOK + kvn + 16 + 4 * g);

        // V^T A-fragments: slot i = t*4+r  <->  kv = kv0 + 16t + 4g + r  (matches S^T lane layout)
        bf16x8 vf0, vf1;
        #pragma unroll
        for (int i = 0; i < 4; ++i) {
            vf0[i] = v00[i]; vf0[4 + i] = v01[i];
            vf1[i] = v10[i]; vf1[4 + i] = v11[i];
        }

        const f32x4 z = {0.f,0.f,0.f,0.f};
        // ---- q-tile 0 ----
        {
            f32x4 s0 = __builtin_amdgcn_mfma_f32_16x16x32_bf16(kf0, qf0, z, 0, 0, 0);
            f32x4 s1 = __builtin_amdgcn_mfma_f32_16x16x32_bf16(kf1, qf0, z, 0, 0, 0);
            float pm = fmaxf(fmaxf(fmaxf(s0[0], s0[1]), fmaxf(s0[2], s0[3])),
                             fmaxf(fmaxf(s1[0], s1[1]), fmaxf(s1[2], s1[3])));
            pm = fmaxf(pm, __shfl_xor(pm, 16));
            pm = fmaxf(pm, __shfl_xor(pm, 32));
            float mnew = fmaxf(m0, pm);
            float sc = exp2f(m0 - mnew);
            m0 = mnew;
            float p0 = exp2f(s0[0] - mnew), p1 = exp2f(s0[1] - mnew);
            float p2 = exp2f(s0[2] - mnew), p3 = exp2f(s0[3] - mnew);
            float p4 = exp2f(s1[0] - mnew), p5 = exp2f(s1[1] - mnew);
            float p6 = exp2f(s1[2] - mnew), p7 = exp2f(s1[3] - mnew);
            l0 = l0 * sc + ((p0 + p1) + (p2 + p3)) + ((p4 + p5) + (p6 + p7));
            acc00 *= sc; acc01 *= sc;
            bf16x8 pf;
            pf[0] = (__bf16)p0; pf[1] = (__bf16)p1; pf[2] = (__bf16)p2; pf[3] = (__bf16)p3;
            pf[4] = (__bf16)p4; pf[5] = (__bf16)p5; pf[6] = (__bf16)p6; pf[7] = (__bf16)p7;
            acc00 = __builtin_amdgcn_mfma_f32_16x16x32_bf16(vf0, pf, acc00, 0, 0, 0);
            acc01 = __builtin_amdgcn_mfma_f32_16x16x32_bf16(vf1, pf, acc01, 0, 0, 0);
        }
        // ---- q-tile 1 ----
        {
            f32x4 s0 = __builtin_amdgcn_mfma_f32_16x16x32_bf16(kf0, qf1, z, 0, 0, 0);
            f32x4 s1 = __builtin_amdgcn_mfma_f32_16x16x32_bf16(kf1, qf1, z, 0, 0, 0);
            float pm = fmaxf(fmaxf(fmaxf(s0[0], s0[1]), fmaxf(s0[2], s0[3])),
                             fmaxf(fmaxf(s1[0], s1[1]), fmaxf(s1[2], s1[3])));
            pm = fmaxf(pm, __shfl_xor(pm, 16));
            pm = fmaxf(pm, __shfl_xor(pm, 32));
            float mnew = fmaxf(m1, pm);
            float sc = exp2f(m1 - mnew);
            m1 = mnew;
            float p0 = exp2f(s0[0] - mnew), p1 = exp2f(s0[1] - mnew);
            float p2 = exp2f(s0[2] - mnew), p3 = exp2f(s0[3] - mnew);
            float p4 = exp2f(s1[0] - mnew), p5 = exp2f(s1[1] - mnew);
            float p6 = exp2f(s1[2] - mnew), p7 = exp2f(s1[3] - mnew);
            l1 = l1 * sc + ((p0 + p1) + (p2 + p3)) + ((p4 + p5) + (p6 + p7));
            acc10 *= sc; acc11 *= sc;
            bf16x8 pf;
            pf[0] = (__bf16)p0; pf[1] = (__bf16)p1; pf[2] = (__bf16)p2; pf[3] = (__bf16)p3;
            pf[4] = (__bf16)p4; pf[5] = (__bf16)p5; pf[6] = (__bf16)p6; pf[7] = (__bf16)p7;
            acc10 = __builtin_amdgcn_mfma_f32_16x16x32_bf16(vf0, pf, acc10, 0, 0, 0);
            acc11 = __builtin_amdgcn_mfma_f32_16x16x32_bf16(vf1, pf, acc11, 0, 0, 0);
        }
        kf0 = nkf0; kf1 = nkf1;
        v00 = nv00; v01 = nv01; v10 = nv10; v11 = nv11;
    }

    // final row-sum reduce across the 4 lanes holding each q-row, then normalize + store out^T
    l0 += __shfl_xor(l0, 16); l0 += __shfl_xor(l0, 32);
    l1 += __shfl_xor(l1, 16); l1 += __shfl_xor(l1, 32);
    const float inv0 = 1.f / l0, inv1 = 1.f / l1;
    float* otb = ot + (size_t)bh * 32 * NTOK;   // out^T[b][c=h*32+d][n]
    #pragma unroll
    for (int r = 0; r < 4; ++r) {
        otb[(size_t)(4 * g + r) * NTOK + q0 + ql]           = acc00[r] * inv0;
        otb[(size_t)(16 + 4 * g + r) * NTOK + q0 + ql]      = acc01[r] * inv0;
        otb[(size_t)(4 * g + r) * NTOK + q0 + 16 + ql]      = acc10[r] * inv1;
        otb[(size_t)(16 + 4 * g + r) * NTOK + q0 + 16 + ql] = acc11[r] * inv1;
    }
}

// ---------------- Kernel 3: output projection (fp32) ----------------
__global__ __launch_bounds__(256) void out_proj_kernel(const float* __restrict__ ot,
                                                       const float* __restrict__ w,
                                                       const float* __restrict__ bias,
                                                       float* __restrict__ y)
{
    __shared__ float t[128 * 64];
    const int bid = blockIdx.x;          // 256 blocks: b(2) x ntile(64) x osplit(2)
    const int os  = bid & 1;
    const int nt  = (bid >> 1) & 63;
    const int b   = bid >> 7;
    const int n0  = nt * 64;
    const int tid = threadIdx.x;
    const float* ob = ot + (size_t)b * 128 * NTOK + n0;
    for (int idx = tid; idx < 128 * 64; idx += 256) {
        int c = idx >> 6, j = idx & 63;
        t[idx] = ob[(size_t)c * NTOK + j];
    }
    __syncthreads();
    const int j = tid & 63, wrow = tid >> 6;
    const int n = n0 + j;
    for (int kk = 0; kk < 16; kk += 8) {
        float a[8] = {0.f,0.f,0.f,0.f,0.f,0.f,0.f,0.f};
        for (int c = 0; c < 128; ++c) {
            float xv = t[c * 64 + j];
            #pragma unroll
            for (int u = 0; u < 8; ++u) {
                const int o = os * 64 + (kk + u) * 4 + wrow;
                a[u] = fmaf(w[o * 128 + c], xv, a[u]);
            }
        }
        #pragma unroll
        for (int u = 0; u < 8; ++u) {
            const int o = os * 64 + (kk + u) * 4 + wrow;
            y[((size_t)b * 128 + o) * NTOK + n] = a[u] + bias[o];
        }
    }
}

extern "C" void kernel_launch(void* const* d_in, const int* in_sizes, int n_in,
                              void* d_out, int out_size, void* d_ws, size_t ws_size,
                              hipStream_t stream) {
    const float* x     = (const float*)d_in[0];
    const float* w_qkv = (const float*)d_in[1];
    const float* w_out = (const float*)d_in[2];
    const float* b_out = (const float*)d_in[3];
    float* y = (float*)d_out;

    // workspace layout: Q (2MB) | K (2MB) | VT (2MB) | outT fp32 (4MB)
    __bf16* Qb = (__bf16*)d_ws;
    __bf16* Kb = Qb + (size_t)8 * NTOK * DHEAD;
    __bf16* Vb = Kb + (size_t)8 * NTOK * DHEAD;
    float*  ot = (float*)(Vb + (size_t)8 * NTOK * DHEAD);

    hipLaunchKernelGGL(qkv_proj_kernel, dim3(256), dim3(256), 0, stream, x, w_qkv, Qb, Kb, Vb);
    hipLaunchKernelGGL(attn_kernel, dim3(1024), dim3(64), 0, stream, Qb, Kb, Vb, ot);
    hipLaunchKernelGGL(out_proj_kernel, dim3(256), dim3(256), 0, stream, ot, w_out, b_out, y);
}

// Round 3
// 164.554 us; speedup vs baseline: 1.5108x; 1.5108x over previous
//
#include <hip/hip_runtime.h>
#include <hip/hip_bf16.h>
#include <math.h>

typedef __attribute__((ext_vector_type(8))) __bf16 bf16x8;
typedef __attribute__((ext_vector_type(4))) __bf16 bf16x4;
typedef __attribute__((ext_vector_type(4))) float f32x4;

#define NTOK 4096
#define DHEAD 32
#define MBIAS 12.0f
#define QSCALE 0.2550316626f   // log2(e)/sqrt(32)

static __device__ __forceinline__ float fexp2(float x) {
    return __builtin_amdgcn_exp2f(x);
}

// ---------------- Kernel A: split x (fp32 [b][c][n]) -> xh/xl (bf16 [b*n][c]) ----------------
// Transpose is free: per-c loads are coalesced across lanes (lane -> n), writes contiguous in c.
__global__ __launch_bounds__(256) void split_x_kernel(const float* __restrict__ x,
                                                      __bf16* __restrict__ xh,
                                                      __bf16* __restrict__ xl)
{
    const int tid  = threadIdx.x;
    const int w    = tid >> 6, lane = tid & 63;
    const int n    = blockIdx.x * 128 + (w >> 1) * 64 + lane;  // global n in [0,8192)
    const int c0   = (w & 1) * 64;
    const int b    = n >> 12;
    const int nn   = n & (NTOK - 1);
    const float* xp = x + ((size_t)b * 128 + c0) * NTOK + nn;
    __bf16* hp = xh + (size_t)n * 128 + c0;
    __bf16* lp = xl + (size_t)n * 128 + c0;
    for (int i0 = 0; i0 < 64; i0 += 8) {
        bf16x8 h8, l8;
        #pragma unroll
        for (int i = 0; i < 8; ++i) {
            float v = xp[(size_t)(i0 + i) * NTOK];
            __bf16 h = (__bf16)v;
            h8[i] = h;
            l8[i] = (__bf16)(v - (float)h);
        }
        *(bf16x8*)(hp + i0) = h8;
        *(bf16x8*)(lp + i0) = l8;
    }
}

// ---------------- Kernel B: QKV projection via split-bf16 MFMA ----------------
// qkv[o][n] = sum_c w[o][c] x[c][n]; 3 passes (wh*xh + wl*xh + wh*xl) ~ fp32 accuracy.
// A = w rows (split on the fly), B = xt rows-as-columns. D: row=o (4g+r), col=n (ql).
__global__ __launch_bounds__(256) void qkv_mfma_kernel(const __bf16* __restrict__ xh,
                                                       const __bf16* __restrict__ xl,
                                                       const float* __restrict__ w,
                                                       __bf16* __restrict__ Qo,
                                                       __bf16* __restrict__ Ko,
                                                       __bf16* __restrict__ Vo)
{
    const int bid   = blockIdx.x;        // 768 = 6 otiles * 128 ntiles
    const int ot    = bid % 6;
    const int ntile = bid / 6;
    const int tid   = threadIdx.x;
    const int wv    = tid >> 6, lane = tid & 63;
    const int g = lane >> 4, ql = lane & 15;
    const int o0 = ot * 64 + wv * 16;
    const int n0 = ntile * 64;

    f32x4 acc[4] = {{0.f,0.f,0.f,0.f},{0.f,0.f,0.f,0.f},{0.f,0.f,0.f,0.f},{0.f,0.f,0.f,0.f}};

    #pragma unroll
    for (int kc = 0; kc < 4; ++kc) {
        const float* wp = w + (size_t)(o0 + ql) * 128 + kc * 32 + g * 8;
        f32x4 w0 = *(const f32x4*)wp;
        f32x4 w1 = *(const f32x4*)(wp + 4);
        bf16x8 wh, wl;
        #pragma unroll
        for (int i = 0; i < 4; ++i) {
            float v0 = w0[i], v1 = w1[i];
            __bf16 h0 = (__bf16)v0, h1 = (__bf16)v1;
            wh[i] = h0; wh[4 + i] = h1;
            wl[i] = (__bf16)(v0 - (float)h0);
            wl[4 + i] = (__bf16)(v1 - (float)h1);
        }
        #pragma unroll
        for (int nt = 0; nt < 4; ++nt) {
            const size_t bofs = (size_t)(n0 + nt * 16 + ql) * 128 + kc * 32 + g * 8;
            bf16x8 bh = *(const bf16x8*)(xh + bofs);
            bf16x8 bl = *(const bf16x8*)(xl + bofs);
            acc[nt] = __builtin_amdgcn_mfma_f32_16x16x32_bf16(wh, bh, acc[nt], 0, 0, 0);
            acc[nt] = __builtin_amdgcn_mfma_f32_16x16x32_bf16(wl, bh, acc[nt], 0, 0, 0);
            acc[nt] = __builtin_amdgcn_mfma_f32_16x16x32_bf16(wh, bl, acc[nt], 0, 0, 0);
        }
    }

    const int orow = o0 + 4 * g;   // +r ; branch is uniform across the wave's o-range (64-aligned splits)
    #pragma unroll
    for (int nt = 0; nt < 4; ++nt) {
        const int ng = n0 + nt * 16 + ql;
        const int b = ng >> 12, nn = ng & (NTOK - 1);
        if (orow < 128) {
            const int h = orow >> 5, d0 = orow & 31;
            bf16x4 q4;
            #pragma unroll
            for (int r = 0; r < 4; ++r) q4[r] = (__bf16)(acc[nt][r] * QSCALE);
            *(bf16x4*)(Qo + ((size_t)(b * 4 + h) * NTOK + nn) * DHEAD + d0) = q4;
        } else if (orow < 256) {
            const int oo = orow - 128, h = oo >> 5, d0 = oo & 31;
            bf16x4 k4;
            #pragma unroll
            for (int r = 0; r < 4; ++r) k4[r] = (__bf16)acc[nt][r];
            *(bf16x4*)(Ko + ((size_t)(b * 4 + h) * NTOK + nn) * DHEAD + d0) = k4;
        } else {
            const int oo = orow - 256, h = oo >> 5, d0 = oo & 31;
            #pragma unroll
            for (int r = 0; r < 4; ++r)
                Vo[((size_t)(b * 4 + h) * DHEAD + d0 + r) * NTOK + nn] = (__bf16)acc[nt][r];
        }
    }
}

// ---------------- Kernel C: flash attention, static-max, KVBLK=64, no LDS ----------------
// S' = q.k*log2e - 12 via MFMA C-input; P = exp2(S'); l via all-ones A-operand MFMA.
// Swapped QK^T (A=K rows, B=Q) -> lane-local P; PV with matching k-slot bijection.
__global__ __launch_bounds__(64) void attn_kernel(const __bf16* __restrict__ Q,
                                                  const __bf16* __restrict__ K,
                                                  const __bf16* __restrict__ VT,
                                                  __bf16* __restrict__ oth,
                                                  __bf16* __restrict__ otl)
{
    const int bid = blockIdx.x;          // 1024 = 8 bh * 128 q-groups
    const int bh  = bid >> 7;
    const int qg  = bid & 127;
    const int lane = threadIdx.x;
    const int g = lane >> 4, ql = lane & 15;
    const __bf16* Qb = Q  + (size_t)bh * NTOK * DHEAD;
    const __bf16* Kb = K  + (size_t)bh * NTOK * DHEAD;
    const __bf16* Vb = VT + (size_t)bh * DHEAD * NTOK;
    const int q0 = qg * 32;

    bf16x8 qf[2];
    qf[0] = *(const bf16x8*)(Qb + (size_t)(q0 + ql) * DHEAD + 8 * g);
    qf[1] = *(const bf16x8*)(Qb + (size_t)(q0 + 16 + ql) * DHEAD + 8 * g);

    f32x4 acc[2][2] = {};     // [qt][dt] numerators of out^T
    f32x4 accl[2]   = {};     // row-sums l via ones-MFMA
    const f32x4 mneg = {-MBIAS, -MBIAS, -MBIAS, -MBIAS};
    bf16x8 ones;
    #pragma unroll
    for (int i = 0; i < 8; ++i) ones[i] = (__bf16)1.0f;

    const __bf16* krow  = Kb + (size_t)ql * DHEAD + 8 * g;      // + kv*32
    const __bf16* vrow0 = Vb + (size_t)ql * NTOK;               // d = ql      (+ kv)
    const __bf16* vrow1 = Vb + (size_t)(16 + ql) * NTOK;        // d = 16+ql

    bf16x8 kf[4];
    bf16x4 va[2][4];   // [dt][kt], at kv offset 16*kt + 4g
    #pragma unroll
    for (int t = 0; t < 4; ++t) kf[t] = *(const bf16x8*)(krow + (size_t)(16 * t) * DHEAD);
    #pragma unroll
    for (int t = 0; t < 4; ++t) {
        va[0][t] = *(const bf16x4*)(vrow0 + 16 * t + 4 * g);
        va[1][t] = *(const bf16x4*)(vrow1 + 16 * t + 4 * g);
    }

    for (int kv0 = 0; kv0 < NTOK; kv0 += 64) {
        const int kvn = (kv0 + 64) & (NTOK - 1);   // wraps on last iter; in-bounds, values unused
        bf16x8 nkf[4];
        bf16x4 nva[2][4];
        #pragma unroll
        for (int t = 0; t < 4; ++t)
            nkf[t] = *(const bf16x8*)(krow + (size_t)(kvn + 16 * t) * DHEAD);
        #pragma unroll
        for (int t = 0; t < 4; ++t) {
            nva[0][t] = *(const bf16x4*)(vrow0 + kvn + 16 * t + 4 * g);
            nva[1][t] = *(const bf16x4*)(vrow1 + kvn + 16 * t + 4 * g);
        }

        // V^T A-fragments: slot j (j<4 -> kv 32kp+4g+j ; j>=4 -> 32kp+16+4g+j-4)
        bf16x8 vf[2][2];
        #pragma unroll
        for (int dt = 0; dt < 2; ++dt) {
            vf[dt][0] = __builtin_shufflevector(va[dt][0], va[dt][1], 0,1,2,3,4,5,6,7);
            vf[dt][1] = __builtin_shufflevector(va[dt][2], va[dt][3], 0,1,2,3,4,5,6,7);
        }

        #pragma unroll
        for (int qt = 0; qt < 2; ++qt) {
            f32x4 s[4];
            #pragma unroll
            for (int t = 0; t < 4; ++t)
                s[t] = __builtin_amdgcn_mfma_f32_16x16x32_bf16(kf[t], qf[qt], mneg, 0, 0, 0);
            // P = exp2(S') ; pack into B-fragments with the matching k-slot bijection
            bf16x8 pf0, pf1;
            #pragma unroll
            for (int r = 0; r < 4; ++r) {
                pf0[r]     = (__bf16)fexp2(s[0][r]);
                pf0[4 + r] = (__bf16)fexp2(s[1][r]);
                pf1[r]     = (__bf16)fexp2(s[2][r]);
                pf1[4 + r] = (__bf16)fexp2(s[3][r]);
            }
            acc[qt][0] = __builtin_amdgcn_mfma_f32_16x16x32_bf16(vf[0][0], pf0, acc[qt][0], 0, 0, 0);
            acc[qt][1] = __builtin_amdgcn_mfma_f32_16x16x32_bf16(vf[1][0], pf0, acc[qt][1], 0, 0, 0);
            accl[qt]   = __builtin_amdgcn_mfma_f32_16x16x32_bf16(ones,     pf0, accl[qt],   0, 0, 0);
            acc[qt][0] = __builtin_amdgcn_mfma_f32_16x16x32_bf16(vf[0][1], pf1, acc[qt][0], 0, 0, 0);
            acc[qt][1] = __builtin_amdgcn_mfma_f32_16x16x32_bf16(vf[1][1], pf1, acc[qt][1], 0, 0, 0);
            accl[qt]   = __builtin_amdgcn_mfma_f32_16x16x32_bf16(ones,     pf1, accl[qt],   0, 0, 0);
        }

        #pragma unroll
        for (int t = 0; t < 4; ++t) kf[t] = nkf[t];
        #pragma unroll
        for (int t = 0; t < 4; ++t) { va[0][t] = nva[0][t]; va[1][t] = nva[1][t]; }
    }

    // epilogue: normalize, split hi/lo, store token-major out [b][n][128]
    const int b = bh >> 2, h = bh & 3;
    #pragma unroll
    for (int qt = 0; qt < 2; ++qt) {
        const float inv = 1.0f / accl[qt][0];
        const int n = q0 + qt * 16 + ql;
        __bf16* hp = oth + ((size_t)b * NTOK + n) * 128 + h * 32;
        __bf16* lp = otl + ((size_t)b * NTOK + n) * 128 + h * 32;
        #pragma unroll
        for (int dt = 0; dt < 2; ++dt) {
            bf16x4 h4, l4;
            #pragma unroll
            for (int r = 0; r < 4; ++r) {
                float v = acc[qt][dt][r] * inv;
                __bf16 hh = (__bf16)v;
                h4[r] = hh;
                l4[r] = (__bf16)(v - (float)hh);
            }
            *(bf16x4*)(hp + dt * 16 + 4 * g) = h4;
            *(bf16x4*)(lp + dt * 16 + 4 * g) = l4;
        }
    }
}

// ---------------- Kernel D: output projection via split-bf16 MFMA + bias ----------------
__global__ __launch_bounds__(256) void out_mfma_kernel(const __bf16* __restrict__ oh,
                                                       const __bf16* __restrict__ ol,
                                                       const float* __restrict__ w,
                                                       const float* __restrict__ bias,
                                                       float* __restrict__ y)
{
    const int bid   = blockIdx.x;        // 256 = 2 otiles * 128 ntiles
    const int ot    = bid & 1;
    const int ntile = bid >> 1;
    const int tid   = threadIdx.x;
    const int wv    = tid >> 6, lane = tid & 63;
    const int g = lane >> 4, ql = lane & 15;
    const int o0 = ot * 64 + wv * 16;
    const int n0 = ntile * 64;

    f32x4 acc[4] = {{0.f,0.f,0.f,0.f},{0.f,0.f,0.f,0.f},{0.f,0.f,0.f,0.f},{0.f,0.f,0.f,0.f}};

    #pragma unroll
    for (int kc = 0; kc < 4; ++kc) {
        const float* wp = w + (size_t)(o0 + ql) * 128 + kc * 32 + g * 8;
        f32x4 w0 = *(const f32x4*)wp;
        f32x4 w1 = *(const f32x4*)(wp + 4);
        bf16x8 wh, wl;
        #pragma unroll
        for (int i = 0; i < 4; ++i) {
            float v0 = w0[i], v1 = w1[i];
            __bf16 h0 = (__bf16)v0, h1 = (__bf16)v1;
            wh[i] = h0; wh[4 + i] = h1;
            wl[i] = (__bf16)(v0 - (float)h0);
            wl[4 + i] = (__bf16)(v1 - (float)h1);
        }
        #pragma unroll
        for (int nt = 0; nt < 4; ++nt) {
            const size_t bofs = (size_t)(n0 + nt * 16 + ql) * 128 + kc * 32 + g * 8;
            bf16x8 bh = *(const bf16x8*)(oh + bofs);
            bf16x8 bl = *(const bf16x8*)(ol + bofs);
            acc[nt] = __builtin_amdgcn_mfma_f32_16x16x32_bf16(wh, bh, acc[nt], 0, 0, 0);
            acc[nt] = __builtin_amdgcn_mfma_f32_16x16x32_bf16(wl, bh, acc[nt], 0, 0, 0);
            acc[nt] = __builtin_amdgcn_mfma_f32_16x16x32_bf16(wh, bl, acc[nt], 0, 0, 0);
        }
    }

    const int orow = o0 + 4 * g;
    float bv[4];
    #pragma unroll
    for (int r = 0; r < 4; ++r) bv[r] = bias[orow + r];
    #pragma unroll
    for (int nt = 0; nt < 4; ++nt) {
        const int ng = n0 + nt * 16 + ql;
        const int b = ng >> 12, nn = ng & (NTOK - 1);
        #pragma unroll
        for (int r = 0; r < 4; ++r)
            y[((size_t)b * 128 + orow + r) * NTOK + nn] = acc[nt][r] + bv[r];
    }
}

extern "C" void kernel_launch(void* const* d_in, const int* in_sizes, int n_in,
                              void* d_out, int out_size, void* d_ws, size_t ws_size,
                              hipStream_t stream) {
    const float* x     = (const float*)d_in[0];
    const float* w_qkv = (const float*)d_in[1];
    const float* w_out = (const float*)d_in[2];
    const float* b_out = (const float*)d_in[3];
    float* y = (float*)d_out;

    // ws layout (10 MB): xh 2MB | xl 2MB | Q 2MB | K 2MB | VT 2MB ; oth/otl alias xh/xl
    char* ws = (char*)d_ws;
    __bf16* xh = (__bf16*)(ws);
    __bf16* xl = (__bf16*)(ws + (size_t)2 * 1024 * 1024);
    __bf16* Qb = (__bf16*)(ws + (size_t)4 * 1024 * 1024);
    __bf16* Kb = (__bf16*)(ws + (size_t)6 * 1024 * 1024);
    __bf16* Vb = (__bf16*)(ws + (size_t)8 * 1024 * 1024);
    __bf16* oth = xh;   // xh/xl dead after qkv_mfma_kernel
    __bf16* otl = xl;

    hipLaunchKernelGGL(split_x_kernel, dim3(64), dim3(256), 0, stream, x, xh, xl);
    hipLaunchKernelGGL(qkv_mfma_kernel, dim3(768), dim3(256), 0, stream, xh, xl, w_qkv, Qb, Kb, Vb);
    hipLaunchKernelGGL(attn_kernel, dim3(1024), dim3(64), 0, stream, Qb, Kb, Vb, oth, otl);
    hipLaunchKernelGGL(out_mfma_kernel, dim3(256), dim3(256), 0, stream, oth, otl, w_out, b_out, y);
}